// Round 1
// baseline (4858.133 us; speedup 1.0000x reference)
//
#include <hip/hip_runtime.h>
#include <cstdint>
#include <cstddef>

// ---------------------------------------------------------------------------
// EGT layer, f32.  N nodes (DIM=96, H=32, HD=3), E edges.
// ---------------------------------------------------------------------------

__device__ __forceinline__ float red32(float v) {
    // reduce within each 32-lane half of the wave (xor masks <= 16 stay inside)
    #pragma unroll
    for (int m = 16; m >= 1; m >>= 1) v += __shfl_xor(v, m, 64);
    return v;
}

// ---------------- row LayerNorm over D=96 ----------------
__global__ __launch_bounds__(256) void ln96_kernel(
    const float* __restrict__ x, const float* __restrict__ g,
    const float* __restrict__ b, float* __restrict__ y, int M)
{
    int lane = threadIdx.x & 31;
    int grp  = threadIdx.x >> 5;
    int r = blockIdx.x * 8 + grp;
    if (r >= M) return;
    const float* xr = x + (size_t)r * 96;
    float a0 = xr[lane], a1 = xr[lane + 32], a2 = xr[lane + 64];
    float mu = red32(a0 + a1 + a2) * (1.f / 96.f);
    float d0 = a0 - mu, d1 = a1 - mu, d2 = a2 - mu;
    float var = red32(d0 * d0 + d1 * d1 + d2 * d2) * (1.f / 96.f);
    float rs = rsqrtf(var + 1e-5f);
    float* yr = y + (size_t)r * 96;
    yr[lane]      = d0 * rs * g[lane]      + b[lane];
    yr[lane + 32] = d1 * rs * g[lane + 32] + b[lane + 32];
    yr[lane + 64] = d2 * rs * g[lane + 64] + b[lane + 64];
}

// ---------------- generic small-N GEMM: C[M,*] = A[M,K] @ B[K,Ncall] + bias --
// AGG: A is the nd accumulator [M,32,5]; col k -> nd[h=k>>2][k&3] / nd[h][4]
// RELU: relu epilogue.  RES: C += scale * resid (resid has layout of C, n0=0).
template<int AGG, int RELU, int RES>
__global__ __launch_bounds__(192) void gemm_kernel(
    const float* __restrict__ A, int lda,
    const float* __restrict__ B, int ldb,
    const float* __restrict__ bias,
    const float* __restrict__ resid,
    const float* __restrict__ wptr,
    float* __restrict__ C, int ldc, int n0,
    int M, int K)
{
    __shared__ float sA[32 * 68];   // [k][m], stride 68 keeps 16B alignment
    __shared__ float sB[32 * 48];   // [k][n]
    const int tid = threadIdx.x;
    const int tx = tid % 12;        // n: 12 * 4 = 48
    const int ty = tid / 12;        // m: 16 * 4 = 64
    const int m0 = blockIdx.x * 64;
    const int nb = blockIdx.y * 48;
    float acc[4][4] = {};

    for (int kc = 0; kc < K; kc += 32) {
        for (int idx = tid; idx < 64 * 32; idx += 192) {
            int m = idx >> 5, k = idx & 31;
            int row = m0 + m;
            float v = 0.f;
            if (row < M) {
                if (AGG) {
                    int col = kc + k;
                    const float* ndr = A + (size_t)row * 160 + (col >> 2) * 5;
                    float den = ndr[4];
                    den = (den != 0.f) ? den : 1.f;
                    v = ndr[col & 3] / den;
                } else {
                    v = A[(size_t)row * lda + kc + k];
                }
            }
            sA[k * 68 + m] = v;
        }
        for (int idx = tid; idx < 32 * 48; idx += 192) {
            int k = idx / 48, n = idx - k * 48;
            sB[idx] = B[(size_t)(kc + k) * ldb + nb + n];
        }
        __syncthreads();
        #pragma unroll
        for (int k = 0; k < 32; k++) {
            float4 av = *(const float4*)&sA[k * 68 + ty * 4];
            float4 bv = *(const float4*)&sB[k * 48 + tx * 4];
            float a4[4] = {av.x, av.y, av.z, av.w};
            float b4[4] = {bv.x, bv.y, bv.z, bv.w};
            #pragma unroll
            for (int i = 0; i < 4; i++)
                #pragma unroll
                for (int j = 0; j < 4; j++)
                    acc[i][j] += a4[i] * b4[j];
        }
        __syncthreads();
    }

    float scale = 1.f;
    if (RES) scale = wptr ? (1.f + wptr[0]) : 1.f;
    #pragma unroll
    for (int i = 0; i < 4; i++) {
        int row = m0 + ty * 4 + i;
        if (row >= M) continue;
        #pragma unroll
        for (int j = 0; j < 4; j++) {
            int col = nb + tx * 4 + j;
            float v = acc[i][j] + bias[col];
            if (RELU) v = fmaxf(v, 0.f);
            if (RES) v += scale * resid[(size_t)row * ldc + n0 + col];
            C[(size_t)row * ldc + n0 + col] = v;
        }
    }
}

// ---------------- edge pass: one 32-lane group per edge ----------------
// Computes ew=LN(edge), B=ew@Wb, ve=ew@We, score, exp; scatters num/den
// atomics into nd[N,32,5]; computes final e output row (score+edge + FFN).
__global__ __launch_bounds__(256) void edge_kernel(
    const float* __restrict__ edge, const float* __restrict__ qkv,
    const int* __restrict__ src, const int* __restrict__ dst,
    const float* __restrict__ We, const float* __restrict__ be,
    const float* __restrict__ Wb, const float* __restrict__ bb,
    const float* __restrict__ Wf0, const float* __restrict__ bf0,
    const float* __restrict__ Wf1, const float* __restrict__ bf1,
    const float* __restrict__ ge0, const float* __restrict__ be0,
    const float* __restrict__ ge1, const float* __restrict__ be1,
    float* __restrict__ nd, float* __restrict__ eout, int E)
{
    __shared__ float sWb[1024], sWe[1024], sWf0[2048], sWf1[2048];
    __shared__ float sbb[32], sbe[32], sbf0[64], sbf1[32];
    __shared__ float sge0[32], sbe0[32], sge1[32], sbe1[32];
    const int tid = threadIdx.x;
    for (int i = tid; i < 1024; i += 256) { sWb[i] = Wb[i]; sWe[i] = We[i]; }
    for (int i = tid; i < 2048; i += 256) { sWf0[i] = Wf0[i]; sWf1[i] = Wf1[i]; }
    if (tid < 32) {
        sbb[tid] = bb[tid]; sbe[tid] = be[tid]; sbf1[tid] = bf1[tid];
        sge0[tid] = ge0[tid]; sbe0[tid] = be0[tid];
        sge1[tid] = ge1[tid]; sbe1[tid] = be1[tid];
    }
    if (tid < 64) sbf0[tid] = bf0[tid];
    __syncthreads();

    const int lane = tid & 31;
    const int grp  = tid >> 5;
    const long long stride = (long long)gridDim.x * 8;

    for (long long e = (long long)blockIdx.x * 8 + grp; e < E; e += stride) {
        float ev = edge[e * 32 + lane];
        // LN(edge) over 32
        float mu = red32(ev) * (1.f / 32.f);
        float d  = ev - mu;
        float var = red32(d * d) * (1.f / 32.f);
        float rs = rsqrtf(var + 1e-5f);
        float ew = d * rs * sge0[lane] + sbe0[lane];
        // B = ew@Wb + bb ; ve = ew@We + be
        float accB = sbb[lane], accVe = sbe[lane];
        #pragma unroll
        for (int i = 0; i < 32; i++) {
            float ewi = __shfl(ew, i, 32);
            accB  += ewi * sWb[i * 32 + lane];
            accVe += ewi * sWe[i * 32 + lane];
        }
        int sn = src[e], dn = dst[e];
        const float* qrow = qkv + (size_t)dn * 288;        // q
        const float* krow = qkv + (size_t)sn * 288 + 96;   // k
        const float* vrow = qkv + (size_t)sn * 288 + 192;  // v
        float q0 = qrow[lane * 3], q1 = qrow[lane * 3 + 1], q2 = qrow[lane * 3 + 2];
        float k0 = krow[lane * 3], k1 = krow[lane * 3 + 1], k2 = krow[lane * 3 + 2];
        float v0 = vrow[lane * 3], v1 = vrow[lane * 3 + 1], v2 = vrow[lane * 3 + 2];
        float score = (k0 * q0 + k1 * q1 + k2 * q2) * 0.5f + accB;
        float ex = __expf(score);
        float* ndp = nd + (size_t)dn * 160 + lane * 5;
        atomicAdd(ndp + 0, ex * v0);
        atomicAdd(ndp + 1, ex * v1);
        atomicAdd(ndp + 2, ex * v2);
        atomicAdd(ndp + 3, ex * accVe);
        atomicAdd(ndp + 4, ex);
        // e output: er + FFN(LN(er))
        float er = score + ev;
        float mu2 = red32(er) * (1.f / 32.f);
        float dd = er - mu2;
        float var2 = red32(dd * dd) * (1.f / 32.f);
        float rs2 = rsqrtf(var2 + 1e-5f);
        float en = dd * rs2 * sge1[lane] + sbe1[lane];
        float f0 = sbf0[lane], f1 = sbf0[lane + 32];
        #pragma unroll
        for (int i = 0; i < 32; i++) {
            float eni = __shfl(en, i, 32);
            f0 += eni * sWf0[i * 64 + lane];
            f1 += eni * sWf0[i * 64 + 32 + lane];
        }
        f0 = fmaxf(f0, 0.f);
        f1 = fmaxf(f1, 0.f);
        float acc = sbf1[lane] + er;
        #pragma unroll
        for (int j = 0; j < 32; j++) {
            float a = __shfl(f0, j, 32);
            float b = __shfl(f1, j, 32);
            acc += a * sWf1[j * 32 + lane] + b * sWf1[(32 + j) * 32 + lane];
        }
        eout[e * 32 + lane] = acc;
    }
}

// ---------------------------------------------------------------------------
extern "C" void kernel_launch(void* const* d_in, const int* in_sizes, int n_in,
                              void* d_out, int out_size, void* d_ws, size_t ws_size,
                              hipStream_t stream)
{
    (void)n_in; (void)out_size; (void)ws_size;
    const float* feat = (const float*)d_in[0];
    const float* edge = (const float*)d_in[1];
    const float* Wq   = (const float*)d_in[2];
    const float* bq   = (const float*)d_in[3];
    const float* Wk   = (const float*)d_in[4];
    const float* bk   = (const float*)d_in[5];
    const float* Wv   = (const float*)d_in[6];
    const float* bv   = (const float*)d_in[7];
    const float* We   = (const float*)d_in[8];
    const float* be   = (const float*)d_in[9];
    const float* Wb   = (const float*)d_in[10];
    const float* bb   = (const float*)d_in[11];
    const float* Wvv  = (const float*)d_in[12];
    const float* bvv  = (const float*)d_in[13];
    const float* Wf0  = (const float*)d_in[14];
    const float* bf0  = (const float*)d_in[15];
    const float* Wf1  = (const float*)d_in[16];
    const float* bf1  = (const float*)d_in[17];
    const float* Wm0  = (const float*)d_in[18];
    const float* bm0  = (const float*)d_in[19];
    const float* Wm1  = (const float*)d_in[20];
    const float* bm1  = (const float*)d_in[21];
    const float* g_n0 = (const float*)d_in[22];
    const float* b_n0 = (const float*)d_in[23];
    const float* g_e0 = (const float*)d_in[24];
    const float* b_e0 = (const float*)d_in[25];
    const float* g_e1 = (const float*)d_in[26];
    const float* b_e1 = (const float*)d_in[27];
    const float* g_m  = (const float*)d_in[28];
    const float* b_m  = (const float*)d_in[29];
    const float* wsc  = (const float*)d_in[30];
    const int*   src  = (const int*)d_in[31];
    const int*   dst  = (const int*)d_in[32];

    const int N = in_sizes[0] / 96;
    const int E = in_sizes[1] / 32;

    float* ws   = (float*)d_ws;
    float* qkv  = ws;                                   // N*288
    float* nd   = qkv + (size_t)N * 288;                // N*160 (num[4] + den)
    float* h0   = nd + (size_t)N * 160;                 // N*96 (h0, later hn)
    float* hp   = h0 + (size_t)N * 96;                  // N*96 (h_pre)
    float* tbuf = ws;                                   // N*192, reuses qkv region
    float* hout = (float*)d_out;
    float* eout = (float*)d_out + (size_t)N * 96;

    hipMemsetAsync(nd, 0, (size_t)N * 160 * sizeof(float), stream);

    const int mt = (N + 63) / 64;

    // h0 = LN(feat)
    ln96_kernel<<<(N + 7) / 8, 256, 0, stream>>>(feat, g_n0, b_n0, h0, N);
    // qkv = h0 @ [Wq|Wk|Wv] + [bq|bk|bv]
    gemm_kernel<0,0,0><<<dim3(mt, 2), 192, 0, stream>>>(h0, 96, Wq, 96, bq, nullptr, nullptr, qkv, 288, 0,   N, 96);
    gemm_kernel<0,0,0><<<dim3(mt, 2), 192, 0, stream>>>(h0, 96, Wk, 96, bk, nullptr, nullptr, qkv, 288, 96,  N, 96);
    gemm_kernel<0,0,0><<<dim3(mt, 2), 192, 0, stream>>>(h0, 96, Wv, 96, bv, nullptr, nullptr, qkv, 288, 192, N, 96);
    // edge pass (scatters nd, writes e output)
    edge_kernel<<<3072, 256, 0, stream>>>(edge, qkv, src, dst,
                                          We, be, Wb, bb, Wf0, bf0, Wf1, bf1,
                                          g_e0, b_e0, g_e1, b_e1,
                                          nd, eout, E);
    // h_pre = feat*(1+w) + agg @ Wvv + bvv   (agg = num/den, fused in staging)
    gemm_kernel<1,0,1><<<dim3(mt, 2), 192, 0, stream>>>(nd, 0, Wvv, 96, bvv, feat, wsc, hp, 96, 0, N, 128);
    // hn = LN(h_pre)  (reuse h0 buffer)
    ln96_kernel<<<(N + 7) / 8, 256, 0, stream>>>(hp, g_m, b_m, h0, N);
    // t = relu(hn @ Wm0 + bm0)
    gemm_kernel<0,1,0><<<dim3(mt, 4), 192, 0, stream>>>(h0, 96, Wm0, 192, bm0, nullptr, nullptr, tbuf, 192, 0, N, 96);
    // h_out = h_pre + t @ Wm1 + bm1
    gemm_kernel<0,0,1><<<dim3(mt, 2), 192, 0, stream>>>(tbuf, 192, Wm1, 96, bm1, hp, nullptr, hout, 96, 0, N, 192);
}